// Round 3
// baseline (243.925 us; speedup 1.0000x reference)
//
#include <hip/hip_runtime.h>
#include <stdint.h>

#define N_ROWS 16384
#define M_ROWS 16384
#define KDIM   512
#define BM 128           // 2 waves x 64 rows
#define BNT 64           // cols per bt tile
#define BKP 128          // k per phase (one MFMA K)
#define NCHUNK 8
#define CHUNK_ROWS (M_ROWS / NCHUNK)       // 2048
#define BT_PER_CHUNK (CHUNK_ROWS / BNT)    // 32

typedef int intx4 __attribute__((ext_vector_type(4)));
typedef int intx8 __attribute__((ext_vector_type(8)));
typedef float floatx4 __attribute__((ext_vector_type(4)));

#define UNIT_SCALE 0x7F7F7F7F  // E8M0 exponent 127 -> 2^0 = 1.0 in every byte

__device__ __forceinline__ void async_ld16(const uint8_t* g, uint8_t* l) {
  __builtin_amdgcn_global_load_lds(
      (const __attribute__((address_space(1))) void*)g,
      (__attribute__((address_space(3))) void*)l, 16, 0, 0);
}

// Kernel 1: fp32 -> fp8 e4m3 (unit scale; |x|<=~5.5 fits e4m3 range 448)
// + per-row squared norms in exact fp32. One wave per row.
__global__ void conv_kernel(const float* __restrict__ A, const float* __restrict__ B,
                            uint8_t* __restrict__ Ah8, uint8_t* __restrict__ Bh8,
                            float* __restrict__ sq1, float* __restrict__ sq2) {
  const int lane = threadIdx.x & 63;
  const int wv = threadIdx.x >> 6;
  int row = blockIdx.x * 4 + wv;
  const float* src;
  uint8_t* dst;
  float* sq;
  if (row < N_ROWS) {
    src = A + (size_t)row * KDIM;
    dst = Ah8 + (size_t)row * KDIM;
    sq = sq1 + row;
  } else {
    int r = row - N_ROWS;
    src = B + (size_t)r * KDIM;
    dst = Bh8 + (size_t)r * KDIM;
    sq = sq2 + r;
  }
  const float4* s4 = (const float4*)src;
  float4 v0 = s4[lane * 2];
  float4 v1 = s4[lane * 2 + 1];
  uint32_t w0 = 0, w1 = 0;
  w0 = __builtin_amdgcn_cvt_pk_fp8_f32(v0.x, v0.y, w0, 0);
  w0 = __builtin_amdgcn_cvt_pk_fp8_f32(v0.z, v0.w, w0, 1);
  w1 = __builtin_amdgcn_cvt_pk_fp8_f32(v1.x, v1.y, w1, 0);
  w1 = __builtin_amdgcn_cvt_pk_fp8_f32(v1.z, v1.w, w1, 1);
  uint2 pk = {w0, w1};
  ((uint2*)dst)[lane] = pk;
  float s = v0.x * v0.x + v0.y * v0.y + v0.z * v0.z + v0.w * v0.w
          + v1.x * v1.x + v1.y * v1.y + v1.z * v1.z + v1.w * v1.w;
  #pragma unroll
  for (int off = 32; off; off >>= 1) s += __shfl_down(s, off, 64);
  if (lane == 0) *sq = s;
}

// Kernel 2: fused fp8 GEMM + running-min.
//
// R2 post-mortem: counted-vmcnt alone was NEUTRAL (MfmaUtil 47%) -> staging
// latency was never critical. Counter fit: phase wall 2349 cyc ~= MFMA(1104)
// + LDS(770) + VALU(590) SERIALIZED (phase-locked waves hit each pipe
// together). R3 fix: register-level rolling prefetch of B fragments (bv0/bv1
// double-buffer at j granularity) so all 8 ds_read_b128/phase are issued
// UNDER the previous 4-MFMA cluster (138 cyc pipe time > 120 cyc LDS lat).
// Top-of-phase wait tightens to vmcnt(4) (next buffer must be landed since
// its j=0 fragment is prefetched during the current phase). Never 0 in
// steady state. Buffer safety: all reads of lsB[q] complete before the
// reader's barrier(q+1); the overwrite (stage(q+4)) is issued after
// barrier(q+2) by waves that can only pass it after every wave completed
// those reads.
__global__ void __launch_bounds__(128, 2)
gemm_min_kernel(const uint8_t* __restrict__ Ah8, const uint8_t* __restrict__ Bh8,
                const float* __restrict__ sq2, float* __restrict__ ws_min) {
  __shared__ __align__(16) uint8_t lsB[4][BNT * BKP];   // 4 x 8 KB
  __shared__ __align__(16) float sq2_lds[CHUNK_ROWS];   // 8 KB

  const int tid = threadIdx.x;
  const int lane = tid & 63;
  const int wv = tid >> 6;       // 0..1
  const int fr = lane & 15;
  const int kg = lane >> 4;      // 0..3
  const int frs = fr & 7;

  const int bid = blockIdx.x;
  const int chunk = bid & 7;
  const int rowBase = (bid >> 3) * BM;
  const int colBase0 = chunk * CHUNK_ROWS;

  // Staging: 8 slots of 1KB per phase (slot = 8 cols x 128 B); wave wv does
  // slots [wv*4, wv*4+4). lane -> col-in-slot = lane>>3, chunk s = lane&7,
  // swizzle key = col&7 = lane>>3.
  const int cis = lane >> 3;                       // col in slot
  const int kofs_st = (((lane & 7) ^ cis) << 4);   // swizzled 16B source chunk

  // ---- Persistent A fragments: areg[i][p] = row (rowBase+wv*64+i*16+fr),
  // k = p*128 + kg*32 .. +32 (32 bytes = 8 VGPRs each; 16 frags = 128 VGPRs).
  intx8 areg[4][4];
  {
    const uint8_t* abase = Ah8 + (size_t)(rowBase + wv * 64 + fr) * KDIM + kg * 32;
    #pragma unroll
    for (int i = 0; i < 4; i++)
      #pragma unroll
      for (int p = 0; p < 4; p++) {
        const uint8_t* ap = abase + (size_t)i * 16 * KDIM + p * BKP;
        intx4 lo = *(const intx4*)ap;
        intx4 hi = *(const intx4*)(ap + 16);
        areg[i][p] = __builtin_shufflevector(lo, hi, 0, 1, 2, 3, 4, 5, 6, 7);
      }
  }

  float runmin[4][4];
  #pragma unroll
  for (int i = 0; i < 4; i++)
    #pragma unroll
    for (int r4 = 0; r4 < 4; r4++) runmin[i][r4] = 3.0e38f;

  // Stage one 64-col x 128-k phase (8 KB): 4 wave-calls per wave.
  #define STAGE_B(buf, cb, kbase_)                                            \
    {                                                                         \
      _Pragma("unroll")                                                       \
      for (int c = 0; c < 4; ++c) {                                           \
        const int slot = wv * 4 + c;                                          \
        async_ld16(Bh8 + (size_t)((cb) + slot * 8 + cis) * KDIM +             \
                       (kbase_) + kofs_st,                                    \
                   (buf) + (slot << 10));                                     \
      }                                                                       \
    }

  // B fragment prefetch into registers (2 x ds_read_b128 -> intx8).
  #define PREFETCH_BV(dst, bufptr, jj)                                        \
    {                                                                         \
      const uint8_t* bp_ = (bufptr) + ((jj) * 16 + fr) * BKP;                 \
      intx4 lo_ = *(const intx4*)(bp_ + ((((kg << 1)) ^ frs) << 4));          \
      intx4 hi_ = *(const intx4*)(bp_ + ((((kg << 1) | 1) ^ frs) << 4));      \
      dst = __builtin_shufflevector(lo_, hi_, 0, 1, 2, 3, 4, 5, 6, 7);        \
    }

  #define MFMA4(bv_, jj, pp)                                                  \
    {                                                                         \
      _Pragma("unroll")                                                       \
      for (int i = 0; i < 4; i++)                                             \
        acc[i][jj] = __builtin_amdgcn_mfma_scale_f32_16x16x128_f8f6f4(        \
            areg[i][pp], bv_, acc[i][jj], 0, 0, 0, UNIT_SCALE, 0, UNIT_SCALE);\
    }

  // Prologue: sq2 chunk -> LDS (8 KB, linear both sides), then phases 0,1,2.
  {
    const uint8_t* s2src = (const uint8_t*)(sq2 + colBase0);
    #pragma unroll
    for (int c = 0; c < 4; ++c) {
      const int off = ((wv * 4 + c) << 10);
      async_ld16(s2src + off + lane * 16, ((uint8_t*)sq2_lds) + off);
    }
  }
  STAGE_B(lsB[0], colBase0, 0)
  STAGE_B(lsB[1], colBase0, BKP)
  STAGE_B(lsB[2], colBase0, 2 * BKP)

  // Wait for sq2 + stage(0) (8 newest = stage1,2 still in flight), join,
  // then preload phase-0 j=0 fragment.
  asm volatile("s_waitcnt vmcnt(8)" ::: "memory");
  __builtin_amdgcn_s_barrier();
  __builtin_amdgcn_sched_barrier(0);

  intx8 bv0, bv1;
  PREFETCH_BV(bv0, lsB[0], 0)

  for (int bt = 0; bt < BT_PER_CHUNK; ++bt) {
    const int colBase = colBase0 + bt * BNT;
    floatx4 acc[4][4];
    #pragma unroll
    for (int i = 0; i < 4; i++)
      #pragma unroll
      for (int j = 0; j < 4; j++) acc[i][j] = (floatx4){0.f, 0.f, 0.f, 0.f};

    #pragma unroll
    for (int p = 0; p < 4; ++p) {
      // vmcnt(4): stage(g+1) landed (its j=0 fragment is prefetched this
      // phase); stage(g+2) stays in flight across the barrier. Tail (last
      // two phases of last tile) drains.
      if (bt == BT_PER_CHUNK - 1 && p >= 2) {
        asm volatile("s_waitcnt vmcnt(0)" ::: "memory");
      } else {
        asm volatile("s_waitcnt vmcnt(4)" ::: "memory");
      }
      __builtin_amdgcn_s_barrier();
      __builtin_amdgcn_sched_barrier(0);

      // Stage phase g+3 into lsB[(p+3)&3].
      if (p == 0) {
        STAGE_B(lsB[3], colBase, 3 * BKP)
      } else if (bt + 1 < BT_PER_CHUNK) {
        STAGE_B(lsB[(p + 3) & 3], colBase + BNT, (p - 1) * BKP)
      }

      const uint8_t* cur = lsB[p];
      const uint8_t* nxt = (p < 3) ? lsB[p + 1] : lsB[0];

      __builtin_amdgcn_s_setprio(1);
      // Rolling register prefetch: ds_reads for fragment j+1 issue under the
      // 4-MFMA cluster for fragment j (138 cyc pipe > 120 cyc LDS latency).
      PREFETCH_BV(bv1, cur, 1)
      MFMA4(bv0, 0, p)
      PREFETCH_BV(bv0, cur, 2)
      MFMA4(bv1, 1, p)
      PREFETCH_BV(bv1, cur, 3)
      MFMA4(bv0, 2, p)
      if (!(p == 3 && bt == BT_PER_CHUNK - 1)) {
        PREFETCH_BV(bv0, nxt, 0)   // j=0 of the NEXT phase's buffer
      }
      MFMA4(bv1, 3, p)
      __builtin_amdgcn_s_setprio(0);
    }

    // Epilogue: cand = sq2[col] - 2*inner -> per-row running min.
    // sq2 read from LDS (no vmcnt pollution).
    // C frag: col = j*16 + fr, row = wv*64 + i*16 + kg*4 + reg.
    #pragma unroll
    for (int j = 0; j < 4; j++) {
      const float s2 = sq2_lds[bt * BNT + j * 16 + fr];
      #pragma unroll
      for (int i = 0; i < 4; i++)
        #pragma unroll
        for (int r4 = 0; r4 < 4; r4++) {
          const float cand = fmaf(-2.f, acc[i][j][r4], s2);
          runmin[i][r4] = fminf(runmin[i][r4], cand);
        }
    }
  }

  // Min over the 16 columns per lane row-group: butterfly on lane bits 0..3.
  #pragma unroll
  for (int i = 0; i < 4; i++)
    #pragma unroll
    for (int r4 = 0; r4 < 4; r4++) {
      float v = runmin[i][r4];
      v = fminf(v, __shfl_xor(v, 1, 64));
      v = fminf(v, __shfl_xor(v, 2, 64));
      v = fminf(v, __shfl_xor(v, 4, 64));
      v = fminf(v, __shfl_xor(v, 8, 64));
      runmin[i][r4] = v;
    }

  if (fr == 0) {
    #pragma unroll
    for (int i = 0; i < 4; i++)
      #pragma unroll
      for (int r4 = 0; r4 < 4; r4++) {
        const int lrow = wv * 64 + i * 16 + kg * 4 + r4;
        ws_min[(size_t)chunk * N_ROWS + rowBase + lrow] = runmin[i][r4];
      }
  }
}

// Kernel 3a: per-row min across chunks + sqrt/relu, 64-block partial sums.
__global__ void partial_kernel(const float* __restrict__ ws_min,
                               const float* __restrict__ sq1,
                               float* __restrict__ part) {
  const int r = blockIdx.x * 256 + threadIdx.x;
  float m = ws_min[r];
  #pragma unroll
  for (int c = 1; c < NCHUNK; c++) m = fminf(m, ws_min[(size_t)c * N_ROWS + r]);
  float d2 = sq1[r] + m;
  d2 = d2 > 0.f ? d2 : 0.f;
  float v = sqrtf(d2) - 0.1f;
  float s = v > 0.f ? v : 0.f;
  #pragma unroll
  for (int off = 32; off; off >>= 1) s += __shfl_down(s, off, 64);
  __shared__ float ps[4];
  if ((threadIdx.x & 63) == 0) ps[threadIdx.x >> 6] = s;
  __syncthreads();
  if (threadIdx.x == 0) part[blockIdx.x] = ps[0] + ps[1] + ps[2] + ps[3];
}

// Kernel 3b: combine 64 partials.
__global__ void final_kernel(const float* __restrict__ part, float* __restrict__ out) {
  float s = part[threadIdx.x];
  #pragma unroll
  for (int off = 32; off; off >>= 1) s += __shfl_down(s, off, 64);
  if (threadIdx.x == 0) out[0] = s / (float)N_ROWS;
}

extern "C" void kernel_launch(void* const* d_in, const int* in_sizes, int n_in,
                              void* d_out, int out_size, void* d_ws, size_t ws_size,
                              hipStream_t stream) {
  const float* A = (const float*)d_in[0];
  const float* B = (const float*)d_in[1];
  char* ws = (char*)d_ws;
  const size_t fp8Bytes = (size_t)N_ROWS * KDIM;   // 8 MiB each
  uint8_t* Ah8 = (uint8_t*)ws;
  uint8_t* Bh8 = (uint8_t*)(ws + fp8Bytes);
  float* sq1 = (float*)(ws + 2 * fp8Bytes);
  float* sq2 = sq1 + N_ROWS;
  float* ws_min = sq2 + M_ROWS;
  float* part = ws_min + (size_t)NCHUNK * N_ROWS;

  conv_kernel<<<dim3((N_ROWS + M_ROWS) / 4), dim3(256), 0, stream>>>(A, B, Ah8, Bh8, sq1, sq2);
  gemm_min_kernel<<<dim3((N_ROWS / BM) * NCHUNK), dim3(128), 0, stream>>>(Ah8, Bh8, sq2, ws_min);
  partial_kernel<<<dim3(64), dim3(256), 0, stream>>>(ws_min, sq1, part);
  final_kernel<<<dim3(1), dim3(64), 0, stream>>>(part, (float*)d_out);
}

// Round 4
// 191.853 us; speedup vs baseline: 1.2714x; 1.2714x over previous
//
#include <hip/hip_runtime.h>
#include <stdint.h>

#define N_ROWS 16384
#define M_ROWS 16384
#define KDIM   512
#define BM 256           // 4 waves x 64 rows
#define BNT 64           // cols per bt tile
#define BKP 128          // k per phase-sub-buffer (one MFMA K)
#define NCHUNK 8
#define CHUNK_ROWS (M_ROWS / NCHUNK)       // 2048
#define BT_PER_CHUNK (CHUNK_ROWS / BNT)    // 32

typedef int intx4 __attribute__((ext_vector_type(4)));
typedef int intx8 __attribute__((ext_vector_type(8)));
typedef float floatx4 __attribute__((ext_vector_type(4)));

#define UNIT_SCALE 0x7F7F7F7F  // E8M0 exponent 127 -> 2^0 = 1.0 in every byte

__device__ __forceinline__ void async_ld16(const uint8_t* g, uint8_t* l) {
  __builtin_amdgcn_global_load_lds(
      (const __attribute__((address_space(1))) void*)g,
      (__attribute__((address_space(3))) void*)l, 16, 0, 0);
}

// Kernel 1: fp32 -> fp8 e4m3 (unit scale; |x|<=~5.5 fits e4m3 range 448)
// + per-row squared norms in exact fp32. One wave per row.
__global__ void conv_kernel(const float* __restrict__ A, const float* __restrict__ B,
                            uint8_t* __restrict__ Ah8, uint8_t* __restrict__ Bh8,
                            float* __restrict__ sq1, float* __restrict__ sq2) {
  const int lane = threadIdx.x & 63;
  const int wv = threadIdx.x >> 6;
  int row = blockIdx.x * 4 + wv;
  const float* src;
  uint8_t* dst;
  float* sq;
  if (row < N_ROWS) {
    src = A + (size_t)row * KDIM;
    dst = Ah8 + (size_t)row * KDIM;
    sq = sq1 + row;
  } else {
    int r = row - N_ROWS;
    src = B + (size_t)r * KDIM;
    dst = Bh8 + (size_t)r * KDIM;
    sq = sq2 + r;
  }
  const float4* s4 = (const float4*)src;
  float4 v0 = s4[lane * 2];
  float4 v1 = s4[lane * 2 + 1];
  uint32_t w0 = 0, w1 = 0;
  w0 = __builtin_amdgcn_cvt_pk_fp8_f32(v0.x, v0.y, w0, 0);
  w0 = __builtin_amdgcn_cvt_pk_fp8_f32(v0.z, v0.w, w0, 1);
  w1 = __builtin_amdgcn_cvt_pk_fp8_f32(v1.x, v1.y, w1, 0);
  w1 = __builtin_amdgcn_cvt_pk_fp8_f32(v1.z, v1.w, w1, 1);
  uint2 pk = {w0, w1};
  ((uint2*)dst)[lane] = pk;
  float s = v0.x * v0.x + v0.y * v0.y + v0.z * v0.z + v0.w * v0.w
          + v1.x * v1.x + v1.y * v1.y + v1.z * v1.z + v1.w * v1.w;
  #pragma unroll
  for (int off = 32; off; off >>= 1) s += __shfl_down(s, off, 64);
  if (lane == 0) *sq = s;
}

// Kernel 2: fused fp8 GEMM + running-min, TILE-granular double buffer.
//
// R3 post-mortem: register rolling-prefetch spilled (WRITE_SIZE 4.6->26MB).
// R1/R2 model: per-phase wall 2349 cyc = MFMA(1104)+LDS(~670)+VALU(~580)
// fully SERIALIZED; 4 barriers/tile re-serialize 128x; ~1.6 waves/SIMD gives
// no TLP. R4 design: BM=256 (4 waves x 64 rows), B tile = 64 cols x K=512
// (32 KB) double-buffered at TILE level. ONE vmcnt(0)+s_barrier per
// 64-MFMA tile; stage(t+1) issues at tile top and has the whole ~2200-cyc
// compute body to land (compute >> L2 latency, so the per-tile drain is
// free). Compute body = straight-line 32 ds_read_b128 + 64 independent-acc
// MFMAs -> compiler's fine lgkmcnt scheduling can hoist reads under MFMAs
// with no barrier in the way. BM=256 halves staging per CU; B-fragment LDS
// reads per CU unchanged (row-count-free). LDS 72 KB -> 2 blocks/CU,
// 8 waves/CU (register cap: areg 128 VGPR + acc 64 AGPR ~ 192/wave).
__global__ void __launch_bounds__(256, 2)
gemm_min_kernel(const uint8_t* __restrict__ Ah8, const uint8_t* __restrict__ Bh8,
                const float* __restrict__ sq2, float* __restrict__ ws_min) {
  __shared__ __align__(16) uint8_t lsB[2][4 * BNT * BKP];   // 2 x 32 KB
  __shared__ __align__(16) float sq2_lds[CHUNK_ROWS];       // 8 KB

  const int tid = threadIdx.x;
  const int lane = tid & 63;
  const int wv = tid >> 6;       // 0..3
  const int fr = lane & 15;
  const int kg = lane >> 4;      // 0..3
  const int frs = fr & 7;

  const int bid = blockIdx.x;
  const int chunk = bid & 7;
  const int rowBase = (bid >> 3) * BM;
  const int colBase0 = chunk * CHUNK_ROWS;

  // Staging: per phase-sub-buffer 8 slots of 1KB (slot = 8 cols x 128 B);
  // wave wv does slots [wv*2, wv*2+2) in each of the 4 sub-buffers
  // (8 calls/wave/tile). lane -> col-in-slot = lane>>3, chunk s = lane&7,
  // swizzle key = col&7 = lane>>3.
  const int cis = lane >> 3;                       // col in slot
  const int kofs_st = (((lane & 7) ^ cis) << 4);   // swizzled 16B source chunk

  // ---- Persistent A fragments: areg[i][p] = row (rowBase+wv*64+i*16+fr),
  // k = p*128 + kg*32 .. +32 (32 bytes = 8 VGPRs each; 16 frags = 128 VGPRs).
  intx8 areg[4][4];
  {
    const uint8_t* abase = Ah8 + (size_t)(rowBase + wv * 64 + fr) * KDIM + kg * 32;
    #pragma unroll
    for (int i = 0; i < 4; i++)
      #pragma unroll
      for (int p = 0; p < 4; p++) {
        const uint8_t* ap = abase + (size_t)i * 16 * KDIM + p * BKP;
        intx4 lo = *(const intx4*)ap;
        intx4 hi = *(const intx4*)(ap + 16);
        areg[i][p] = __builtin_shufflevector(lo, hi, 0, 1, 2, 3, 4, 5, 6, 7);
      }
  }

  float runmin[4][4];
  #pragma unroll
  for (int i = 0; i < 4; i++)
    #pragma unroll
    for (int r4 = 0; r4 < 4; r4++) runmin[i][r4] = 3.0e38f;

  // Stage one full 64-col x K=512 tile (32 KB): 8 calls per wave.
  #define STAGE_TILE(buf, cb)                                                 \
    {                                                                         \
      _Pragma("unroll")                                                       \
      for (int p_ = 0; p_ < 4; ++p_) {                                        \
        _Pragma("unroll")                                                     \
        for (int c_ = 0; c_ < 2; ++c_) {                                      \
          const int slot = wv * 2 + c_;                                       \
          async_ld16(Bh8 + (size_t)((cb) + slot * 8 + cis) * KDIM +           \
                         p_ * BKP + kofs_st,                                  \
                     (buf) + p_ * (BNT * BKP) + (slot << 10));                \
        }                                                                     \
      }                                                                       \
    }

  // Prologue: sq2 chunk -> LDS (8 KB, linear both sides; 2 calls/wave),
  // then stage tile 0.
  {
    const uint8_t* s2src = (const uint8_t*)(sq2 + colBase0);
    #pragma unroll
    for (int c = 0; c < 2; ++c) {
      const int off = ((wv * 2 + c) << 10);
      async_ld16(s2src + off + lane * 16, ((uint8_t*)sq2_lds) + off);
    }
  }
  STAGE_TILE(lsB[0], colBase0)

  for (int bt = 0; bt < BT_PER_CHUNK; ++bt) {
    // All of THIS wave's stages (tile bt + sq2) landed; barrier makes every
    // wave's stages visible. stage(bt+1) is issued after the barrier (its
    // destination buffer was last read in tile bt-1, finished by all waves).
    asm volatile("s_waitcnt vmcnt(0)" ::: "memory");
    __builtin_amdgcn_s_barrier();
    __builtin_amdgcn_sched_barrier(0);

    if (bt + 1 < BT_PER_CHUNK) {
      STAGE_TILE(lsB[(bt + 1) & 1], colBase0 + (bt + 1) * BNT)
    }

    const uint8_t* cur = lsB[bt & 1];
    floatx4 acc[4][4];
    #pragma unroll
    for (int i = 0; i < 4; i++)
      #pragma unroll
      for (int j = 0; j < 4; j++) acc[i][j] = (floatx4){0.f, 0.f, 0.f, 0.f};

    // Straight-line tile body: 32 ds_read_b128 + 64 MFMAs, no barriers.
    __builtin_amdgcn_s_setprio(1);
    #pragma unroll
    for (int p = 0; p < 4; ++p) {
      #pragma unroll
      for (int j = 0; j < 4; ++j) {
        const uint8_t* bp = cur + p * (BNT * BKP) + (j * 16 + fr) * BKP;
        intx4 lo = *(const intx4*)(bp + ((((kg << 1)) ^ frs) << 4));
        intx4 hi = *(const intx4*)(bp + ((((kg << 1) | 1) ^ frs) << 4));
        intx8 bv = __builtin_shufflevector(lo, hi, 0, 1, 2, 3, 4, 5, 6, 7);
        #pragma unroll
        for (int i = 0; i < 4; i++)
          acc[i][j] = __builtin_amdgcn_mfma_scale_f32_16x16x128_f8f6f4(
              areg[i][p], bv, acc[i][j], 0, 0,
              0, UNIT_SCALE, 0, UNIT_SCALE);
      }
    }
    __builtin_amdgcn_s_setprio(0);

    // Epilogue: cand = sq2[col] - 2*inner -> per-row running min.
    // sq2 read from LDS (keeps the vmcnt stream staging-only).
    // C frag: col = j*16 + fr, row = wv*64 + i*16 + kg*4 + reg.
    #pragma unroll
    for (int j = 0; j < 4; j++) {
      const float s2 = sq2_lds[bt * BNT + j * 16 + fr];
      #pragma unroll
      for (int i = 0; i < 4; i++)
        #pragma unroll
        for (int r4 = 0; r4 < 4; r4++) {
          const float cand = fmaf(-2.f, acc[i][j][r4], s2);
          runmin[i][r4] = fminf(runmin[i][r4], cand);
        }
    }
  }

  // Min over the 16 columns per lane row-group: butterfly on lane bits 0..3.
  #pragma unroll
  for (int i = 0; i < 4; i++)
    #pragma unroll
    for (int r4 = 0; r4 < 4; r4++) {
      float v = runmin[i][r4];
      v = fminf(v, __shfl_xor(v, 1, 64));
      v = fminf(v, __shfl_xor(v, 2, 64));
      v = fminf(v, __shfl_xor(v, 4, 64));
      v = fminf(v, __shfl_xor(v, 8, 64));
      runmin[i][r4] = v;
    }

  if (fr == 0) {
    #pragma unroll
    for (int i = 0; i < 4; i++)
      #pragma unroll
      for (int r4 = 0; r4 < 4; r4++) {
        const int lrow = wv * 64 + i * 16 + kg * 4 + r4;
        ws_min[(size_t)chunk * N_ROWS + rowBase + lrow] = runmin[i][r4];
      }
  }
}

// Kernel 3a: per-row min across chunks + sqrt/relu, 64-block partial sums.
__global__ void partial_kernel(const float* __restrict__ ws_min,
                               const float* __restrict__ sq1,
                               float* __restrict__ part) {
  const int r = blockIdx.x * 256 + threadIdx.x;
  float m = ws_min[r];
  #pragma unroll
  for (int c = 1; c < NCHUNK; c++) m = fminf(m, ws_min[(size_t)c * N_ROWS + r]);
  float d2 = sq1[r] + m;
  d2 = d2 > 0.f ? d2 : 0.f;
  float v = sqrtf(d2) - 0.1f;
  float s = v > 0.f ? v : 0.f;
  #pragma unroll
  for (int off = 32; off; off >>= 1) s += __shfl_down(s, off, 64);
  __shared__ float ps[4];
  if ((threadIdx.x & 63) == 0) ps[threadIdx.x >> 6] = s;
  __syncthreads();
  if (threadIdx.x == 0) part[blockIdx.x] = ps[0] + ps[1] + ps[2] + ps[3];
}

// Kernel 3b: combine 64 partials.
__global__ void final_kernel(const float* __restrict__ part, float* __restrict__ out) {
  float s = part[threadIdx.x];
  #pragma unroll
  for (int off = 32; off; off >>= 1) s += __shfl_down(s, off, 64);
  if (threadIdx.x == 0) out[0] = s / (float)N_ROWS;
}

extern "C" void kernel_launch(void* const* d_in, const int* in_sizes, int n_in,
                              void* d_out, int out_size, void* d_ws, size_t ws_size,
                              hipStream_t stream) {
  const float* A = (const float*)d_in[0];
  const float* B = (const float*)d_in[1];
  char* ws = (char*)d_ws;
  const size_t fp8Bytes = (size_t)N_ROWS * KDIM;   // 8 MiB each
  uint8_t* Ah8 = (uint8_t*)ws;
  uint8_t* Bh8 = (uint8_t*)(ws + fp8Bytes);
  float* sq1 = (float*)(ws + 2 * fp8Bytes);
  float* sq2 = sq1 + N_ROWS;
  float* ws_min = sq2 + M_ROWS;
  float* part = ws_min + (size_t)NCHUNK * N_ROWS;

  conv_kernel<<<dim3((N_ROWS + M_ROWS) / 4), dim3(256), 0, stream>>>(A, B, Ah8, Bh8, sq1, sq2);
  gemm_min_kernel<<<dim3((N_ROWS / BM) * NCHUNK), dim3(256), 0, stream>>>(Ah8, Bh8, sq2, ws_min);
  partial_kernel<<<dim3(64), dim3(256), 0, stream>>>(ws_min, sq1, part);
  final_kernel<<<dim3(1), dim3(64), 0, stream>>>(part, (float*)d_out);
}